// Round 9
// baseline (57.951 us; speedup 1.0000x reference)
//
#include <hip/hip_runtime.h>

#define L_LEAVES 8192
#define W_LAMBDA 2101
#define WPAD     2104              // padded table stride (16B-aligned rows)
#define TAB_N    1153              // tau table: 18 octaves * 64 + 1 fencepost (k in [2^-14, 16])
#define SA2_40   0.41317591116653485f
#define LOG2E_F  1.4426950408889634f
#define LN2_F    0.6931471805599453f

__device__ __forceinline__ float rcpf(float x)  { return __builtin_amdgcn_rcpf(x); }
__device__ __forceinline__ float log2f_fast(float x) { return __builtin_amdgcn_logf(x); }
__device__ __forceinline__ float exp2f_fast(float x) { return __builtin_amdgcn_exp2f(x); }
__device__ __forceinline__ float sqrtf_fast(float x) { return __builtin_amdgcn_sqrtf(x); }

// ---- transmissivity of a dielectric plane (Stern / Allen), per-wavelength ----
// fast-intrinsic version (used only in precompute; ~1e-6 rel accuracy, fine vs 2e-2 tol)
__device__ __forceinline__ float getav_dev(float sa2, bool is90, float nr) {
    float n2  = nr * nr;
    float npx = n2 + 1.0f;
    float nm  = n2 - 1.0f;
    float a   = (nr + 1.0f) * (nr + 1.0f) * 0.5f;
    float k   = -(n2 - 1.0f) * (n2 - 1.0f) * 0.25f;
    float b2  = sa2 - npx * 0.5f;
    float b1  = is90 ? 0.0f : sqrtf_fast(b2 * b2 + k);
    float b   = b1 - b2;
    float k2  = k * k;
    float ib  = rcpf(b), ia = rcpf(a);
    float ts  = k2 * (1.0f/6.0f) * (ib*ib*ib) + k * ib - b * 0.5f
              - (k2 * (1.0f/6.0f) * (ia*ia*ia) + k * ia - a * 0.5f);
    float inpx = rcpf(npx);
    float tp1 = -2.0f * n2 * (b - a) * (inpx * inpx);
    float nm2 = nm * nm;
    float inm2 = rcpf(nm2);
    float tp2 = -2.0f * n2 * npx * (LN2_F * log2f_fast(b * ia)) * inm2;
    float tp3 = n2 * (ib - ia) * 0.5f;
    float n22 = n2 * n2;
    float inpx3 = inpx * inpx * inpx;
    float npax_a = 2.0f * npx * a - nm2;
    float npx_b  = 2.0f * npx * b - nm2;
    float tp4 = 16.0f * n22 * (n22 + 1.0f) * (LN2_F * log2f_fast(npx_b * rcpf(npax_a))) * inpx3 * inm2;
    float tp5 = 16.0f * n2 * n2 * n2 * (rcpf(npx_b) - rcpf(npax_a)) * inpx3;
    float tp  = tp1 + tp2 + tp3 + tp4 + tp5;
    return (ts + tp) * rcpf(2.0f * sa2);
}

// tau(k) for table construction (fast intrinsics; abs err ~1e-6)
__device__ __forceinline__ float tau_exact(float k) {
    float ek = exp2f_fast(-k * LOG2E_F);
    float e1;
    if (k <= 1.0f) {
        float poly = fmaf(fmaf(fmaf(fmaf(fmaf(0.00107857f, k, -0.00976004f), k, 0.05519968f),
                        k, -0.24991055f), k, 0.99999193f), k, -0.57721566f);
        e1 = fmaf(-LN2_F, log2f_fast(k), poly);
    } else {
        float pn = fmaf(fmaf(fmaf(k + 8.5733287401f, k, 18.0590169730f),
                       k, 8.6347608925f), k, 0.2677737343f);
        float pd = fmaf(fmaf(fmaf(k + 9.5733223454f, k, 25.6329561486f),
                       k, 21.0996530827f), k, 3.9584969228f);
        e1 = ek * rcpf(k) * (pn * rcpf(pd));
    }
    return fmaf(k * k, e1, (1.0f - k) * ek);
}

__device__ __forceinline__ float bin_k(int w) {
    unsigned e = (unsigned)w >> 6, m = (unsigned)w & 63u;
    return __uint_as_float(((113u + e) << 23) | (m << 17));
}

// d_ws layout: rows 0..4 (WPAD floats each): talf*t21, ralf, t12*t21, r12, r21
// then float2 tau table [TAB_N] at offset 5*WPAD: {tau_i, tau_{i+1}-tau_i}
__global__ void precompute_kernel(const float* __restrict__ nr, float* __restrict__ tab) {
    int w = blockIdx.x * blockDim.x + threadIdx.x;
    if (w < WPAD) {                           // fill pad with clones of last column
        int ws = min(w, W_LAMBDA - 1);
        float n    = nr[ws];
        float talf = getav_dev(SA2_40, false, n);
        float t12  = getav_dev(1.0f,   true,  n);
        float t21  = t12 * rcpf(n * n);
        float r21  = 1.0f - t21;
        tab[0 * WPAD + w] = talf * t21;
        tab[1 * WPAD + w] = 1.0f - talf;
        tab[2 * WPAD + w] = t12 * t21;
        tab[3 * WPAD + w] = 1.0f - t12;
        tab[4 * WPAD + w] = r21;
    }
    if (w < TAB_N) {
        float T0 = tau_exact(bin_k(w));
        float T1 = tau_exact(bin_k(w + 1));
        tab[5 * WPAD + 2 * w]     = T0;
        tab[5 * WPAD + 2 * w + 1] = T1 - T0;
    }
}

struct f4u { float v[4]; };  // 4B-aligned vec4 store (rows start at l*2101 floats)

__device__ __forceinline__ float vget(const float4& v, int j) {
    return j == 0 ? v.x : (j == 1 ? v.y : (j == 2 ? v.z : v.w));
}

template<bool USE_TAB>
__global__ __launch_bounds__(192) void prospect_kernel(
    const float* __restrict__ pN,   const float* __restrict__ pcab,
    const float* __restrict__ pcar, const float* __restrict__ pwater,
    const float* __restrict__ plma, const float* __restrict__ pcant,
    const float* __restrict__ pnr,
    const float* __restrict__ pkab, const float* __restrict__ pkcar,
    const float* __restrict__ pkant, const float* __restrict__ pkw,
    const float* __restrict__ pkm,
    const float* __restrict__ tab,
    float* __restrict__ out_r, float* __restrict__ out_t)
{
    __shared__ float2 TT[TAB_N];
    if (USE_TAB) {
        const float2* src = (const float2*)(tab + 5 * WPAD);
        for (int i = threadIdx.x; i < TAB_N; i += 192)
            TT[i] = src[i];
        __syncthreads();
    }

    const int q  = blockIdx.x * 192 + threadIdx.x;   // quad-of-wavelengths in leaf
    const int w0 = q * 4;
    if (w0 >= W_LAMBDA) return;
    const bool full = (w0 + 4 <= W_LAMBDA);

    const int l = blockIdx.y;          // leaf: wave-uniform -> SGPR trait loads
    const float Nl   = pN[l];
    const float invN = rcpf(Nl);
    const float Nm1  = Nl - 1.0f;
    const float cabl = pcab[l], carl = pcar[l], cantl = pcant[l];
    const float watl = pwater[l], lmal = plma[l];

    float4 vkab, vkcar, vkant, vkw, vkm;
    if (full) {
        vkab  = *(const float4*)(pkab  + w0);
        vkcar = *(const float4*)(pkcar + w0);
        vkant = *(const float4*)(pkant + w0);
        vkw   = *(const float4*)(pkw   + w0);
        vkm   = *(const float4*)(pkm   + w0);
    } else {
        #pragma unroll
        for (int j = 0; j < 4; ++j) {
            int w = min(w0 + j, W_LAMBDA - 1);
            ((float*)&vkab)[j]  = pkab[w];
            ((float*)&vkcar)[j] = pkcar[w];
            ((float*)&vkant)[j] = pkant[w];
            ((float*)&vkw)[j]   = pkw[w];
            ((float*)&vkm)[j]   = pkm[w];
        }
    }
    float4 t0, t1, t2, t3, t4;
    if (USE_TAB) {
        t0 = *(const float4*)(tab + 0 * WPAD + w0);
        t1 = *(const float4*)(tab + 1 * WPAD + w0);
        t2 = *(const float4*)(tab + 2 * WPAD + w0);
        t3 = *(const float4*)(tab + 3 * WPAD + w0);
        t4 = *(const float4*)(tab + 4 * WPAD + w0);
    } else {
        #pragma unroll
        for (int j = 0; j < 4; ++j) {
            int w = min(w0 + j, W_LAMBDA - 1);
            float n    = pnr[w];
            float talf = getav_dev(SA2_40, false, n);
            float t12  = getav_dev(1.0f,   true,  n);
            float t21  = t12 * rcpf(n * n);
            float r21  = 1.0f - t21;
            ((float*)&t0)[j] = talf * t21;
            ((float*)&t1)[j] = 1.0f - talf;
            ((float*)&t2)[j] = t12 * t21;
            ((float*)&t3)[j] = 1.0f - t12;
            ((float*)&t4)[j] = r21;
        }
    }

    float rf[4], tr[4];
    bool anymask = false;
    float kk[4], tauv[4];
    #pragma unroll
    for (int j = 0; j < 4; ++j) {
        // absorption coefficient
        float k = (cabl * vget(vkab, j) + carl * vget(vkcar, j) + cantl * vget(vkant, j)
                 + watl * vget(vkw, j) + lmal * vget(vkm, j)) * invN;
        k = fmaxf(k, 1e-4f);
        kk[j] = k;

        float tau;
        if (USE_TAB) {
            float kc = fminf(k, 15.9f);
            unsigned bits = __float_as_uint(kc);
            int idx = (int)(bits >> 17) - 7232;          // 113<<6
            float frac = (float)(bits & 0x1FFFFu) * (1.0f / 131072.0f);
            float2 T = TT[idx];
            tau = fmaf(frac, T.y, T.x);
        } else {
            tau = tau_exact(k);
        }
        tauv[j] = tau;
    }

    #pragma unroll
    for (int j = 0; j < 4; ++j) {
        const float c0 = vget(t0, j), c1 = vget(t1, j), c2 = vget(t2, j);
        const float c3 = vget(t3, j), c4 = vget(t4, j);
        const float tau = tauv[j];

        // one-layer R/T; denom from (r21*tau)^2
        float r21t = c4 * tau;
        float rd   = rcpf(fmaf(-r21t, r21t, 1.0f));  // 1/(1 - r21^2 tau^2)
        float trd  = tau * rd;
        float Ta   = c0 * trd;                       // talf*t21 * tau / denom
        float tt   = c2 * trd;                       // t12*t21  * tau / denom
        float Ra   = fmaf(r21t, Ta, c1);
        float rr   = fmaf(r21t, tt, c3);

        // Stokes N-1 layers (den2*den3 merged into M)
        float rpt  = rr + tt;
        float rmt  = rr - tt;
        bool  mask = (rpt >= 1.0f);
        anymask = anymask || mask;
        float Dsq  = fmaf(-rmt, rmt, 1.0f) * fmaf(-rpt, rpt, 1.0f);
        float D    = sqrtf_fast(mask ? 1.0f : Dsq);
        float rq   = rpt * rmt;                      // r^2 - t^2
        float s1   = 1.0f + D;
        float rp2  = rcpf((rr * tt) * 4.0f);         // pair-reciprocal 1/(2r),1/(2t)
        float aa   = (s1 + rq) * (rp2 * (tt + tt));
        float bb   = (s1 - rq) * (rp2 * (rr + rr));
        float bsafe = mask ? 1.0f : bb;
        float bnm1 = exp2f_fast(Nm1 * log2f_fast(bsafe));   // b^(N-1)
        float bn2  = bnm1 * bnm1;
        float a2   = aa * aa;
        float den2 = fmaf(a2, bn2, -1.0f);           // a^2 b^{2n} - 1
        float bn2m1 = bn2 - 1.0f;
        float M    = fmaf(-aa * rr, bn2m1, den2);    // den2 - a r (b^{2n}-1) = den2*den3
        float invM = rcpf(M);
        float TaM  = Ta * invM;
        tr[j] = TaM * bnm1 * (a2 - 1.0f);            // Ta*Tsub/den3
        rf[j] = fmaf(TaM * tt * aa, bn2m1, Ra);      // Ra + Ta*Rsub*t/den3
    }

    // rare thick-leaf fixup (never taken for this data): recompute masked points
    if (__any((int)anymask)) {
        #pragma unroll
        for (int j = 0; j < 4; ++j) {
            const float c0 = vget(t0, j), c1 = vget(t1, j), c2 = vget(t2, j);
            const float c3 = vget(t3, j), c4 = vget(t4, j);
            const float tau = tauv[j];
            float r21t = c4 * tau;
            float rd   = rcpf(fmaf(-r21t, r21t, 1.0f));
            float trd  = tau * rd;
            float Ta   = c0 * trd;
            float tt   = c2 * trd;
            float Ra   = fmaf(r21t, Ta, c1);
            float rr   = fmaf(r21t, tt, c3);
            if (rr + tt >= 1.0f) {
                float Talt = tt * rcpf(fmaf(Nm1, 1.0f - tt, tt));
                float Rsm  = 1.0f - Talt;
                float g    = Ta * rcpf(fmaf(-Rsm, rr, 1.0f));
                tr[j] = g * Talt;
                rf[j] = fmaf(g * Rsm, tt, Ra);
            }
        }
    }

    const unsigned base = (unsigned)l * W_LAMBDA + (unsigned)w0;
    if (full) {
        f4u fr; f4u ft;
        #pragma unroll
        for (int j = 0; j < 4; ++j) { fr.v[j] = rf[j]; ft.v[j] = tr[j]; }
        *reinterpret_cast<f4u*>(out_r + base) = fr;
        *reinterpret_cast<f4u*>(out_t + base) = ft;
    } else {
        out_r[base] = rf[0];
        out_t[base] = tr[0];
    }
}

extern "C" void kernel_launch(void* const* d_in, const int* in_sizes, int n_in,
                              void* d_out, int out_size, void* d_ws, size_t ws_size,
                              hipStream_t stream) {
    const float* pN     = (const float*)d_in[0];
    const float* pcab   = (const float*)d_in[1];
    const float* pcar   = (const float*)d_in[2];
    const float* pwater = (const float*)d_in[3];
    const float* plma   = (const float*)d_in[4];
    const float* pcant  = (const float*)d_in[5];
    const float* pnr    = (const float*)d_in[6];
    const float* pkab   = (const float*)d_in[7];
    const float* pkcar  = (const float*)d_in[8];
    const float* pkant  = (const float*)d_in[9];
    const float* pkw    = (const float*)d_in[10];
    const float* pkm    = (const float*)d_in[11];
    float* out_r = (float*)d_out;
    float* out_t = out_r + (size_t)L_LEAVES * W_LAMBDA;

    const int nquads = (W_LAMBDA + 3) / 4;                 // 526
    dim3 grid((nquads + 191) / 192, L_LEAVES);             // (3, 8192)
    dim3 block(192);

    const size_t tab_bytes = (5 * WPAD + 2 * TAB_N) * sizeof(float);
    if (ws_size >= tab_bytes) {
        float* tabp = (float*)d_ws;
        precompute_kernel<<<(WPAD + 63) / 64, 64, 0, stream>>>(pnr, tabp);
        prospect_kernel<true><<<grid, block, 0, stream>>>(
            pN, pcab, pcar, pwater, plma, pcant, pnr,
            pkab, pkcar, pkant, pkw, pkm, (const float*)tabp, out_r, out_t);
    } else {
        prospect_kernel<false><<<grid, block, 0, stream>>>(
            pN, pcab, pcar, pwater, plma, pcant, pnr,
            pkab, pkcar, pkant, pkw, pkm, nullptr, out_r, out_t);
    }
}

// Round 10
// 55.205 us; speedup vs baseline: 1.0497x; 1.0497x over previous
//
#include <hip/hip_runtime.h>
#include <hip/hip_fp16.h>

#define L_LEAVES 8192
#define W_LAMBDA 2101
#define WPAD     2104              // padded table stride (16B-aligned rows)
#define TAB_N    1153              // tau table: 18 octaves * 64 + 1 fencepost (k in [2^-14, 16))
#define SA2_40   0.41317591116653485f
#define LOG2E_F  1.4426950408889634f
#define LN2_F    0.6931471805599453f

__device__ __forceinline__ float rcpf(float x)  { return __builtin_amdgcn_rcpf(x); }
__device__ __forceinline__ float log2f_fast(float x) { return __builtin_amdgcn_logf(x); }
__device__ __forceinline__ float exp2f_fast(float x) { return __builtin_amdgcn_exp2f(x); }
__device__ __forceinline__ float sqrtf_fast(float x) { return __builtin_amdgcn_sqrtf(x); }

// ---- transmissivity of a dielectric plane (Stern / Allen) ----
// fast-intrinsic version (precompute only; ~1e-6 rel accuracy vs 2e-2 tol)
__device__ __forceinline__ float getav_dev(float sa2, bool is90, float nr) {
    float n2  = nr * nr;
    float npx = n2 + 1.0f;
    float nm  = n2 - 1.0f;
    float a   = (nr + 1.0f) * (nr + 1.0f) * 0.5f;
    float k   = -(n2 - 1.0f) * (n2 - 1.0f) * 0.25f;
    float b2  = sa2 - npx * 0.5f;
    float b1  = is90 ? 0.0f : sqrtf_fast(b2 * b2 + k);
    float b   = b1 - b2;
    float k2  = k * k;
    float ib  = rcpf(b), ia = rcpf(a);
    float ts  = k2 * (1.0f/6.0f) * (ib*ib*ib) + k * ib - b * 0.5f
              - (k2 * (1.0f/6.0f) * (ia*ia*ia) + k * ia - a * 0.5f);
    float inpx = rcpf(npx);
    float tp1 = -2.0f * n2 * (b - a) * (inpx * inpx);
    float nm2 = nm * nm;
    float inm2 = rcpf(nm2);
    float tp2 = -2.0f * n2 * npx * (LN2_F * log2f_fast(b * ia)) * inm2;
    float tp3 = n2 * (ib - ia) * 0.5f;
    float n22 = n2 * n2;
    float inpx3 = inpx * inpx * inpx;
    float npax_a = 2.0f * npx * a - nm2;
    float npx_b  = 2.0f * npx * b - nm2;
    float tp4 = 16.0f * n22 * (n22 + 1.0f) * (LN2_F * log2f_fast(npx_b * rcpf(npax_a))) * inpx3 * inm2;
    float tp5 = 16.0f * n2 * n2 * n2 * (rcpf(npx_b) - rcpf(npax_a)) * inpx3;
    float tp  = tp1 + tp2 + tp3 + tp4 + tp5;
    return (ts + tp) * rcpf(2.0f * sa2);
}

// tau(k) for table construction (fast intrinsics; abs err ~1e-6)
__device__ __forceinline__ float tau_exact(float k) {
    float ek = exp2f_fast(-k * LOG2E_F);
    float e1;
    if (k <= 1.0f) {
        float poly = fmaf(fmaf(fmaf(fmaf(fmaf(0.00107857f, k, -0.00976004f), k, 0.05519968f),
                        k, -0.24991055f), k, 0.99999193f), k, -0.57721566f);
        e1 = fmaf(-LN2_F, log2f_fast(k), poly);
    } else {
        float pn = fmaf(fmaf(fmaf(k + 8.5733287401f, k, 18.0590169730f),
                       k, 8.6347608925f), k, 0.2677737343f);
        float pd = fmaf(fmaf(fmaf(k + 9.5733223454f, k, 25.6329561486f),
                       k, 21.0996530827f), k, 3.9584969228f);
        e1 = ek * rcpf(k) * (pn * rcpf(pd));
    }
    return fmaf(k * k, e1, (1.0f - k) * ek);
}

__device__ __forceinline__ float bin_k(int w) {
    unsigned e = (unsigned)w >> 6, m = (unsigned)w & 63u;
    return __uint_as_float(((113u + e) << 23) | (m << 17));
}

// d_ws layout: rows 0..4 (WPAD floats): talf*t21, ralf, t12*t21, r12, r21
// then TAB_N packed half2 {tau_i, tau_{i+1}-tau_i} (one 4B word each) at 5*WPAD
__global__ void precompute_kernel(const float* __restrict__ nr, float* __restrict__ tab) {
    int w = blockIdx.x * blockDim.x + threadIdx.x;
    if (w < WPAD) {                           // pad filled with clones of last column
        int ws = min(w, W_LAMBDA - 1);
        float n    = nr[ws];
        float talf = getav_dev(SA2_40, false, n);
        float t12  = getav_dev(1.0f,   true,  n);
        float t21  = t12 * rcpf(n * n);
        float r21  = 1.0f - t21;
        tab[0 * WPAD + w] = talf * t21;
        tab[1 * WPAD + w] = 1.0f - talf;
        tab[2 * WPAD + w] = t12 * t21;
        tab[3 * WPAD + w] = 1.0f - t12;
        tab[4 * WPAD + w] = r21;
    }
    if (w < TAB_N) {
        float T0 = tau_exact(bin_k(w));
        float T1 = tau_exact(bin_k(w + 1));
        __half2 h2;
        h2.x = __float2half(T0);
        h2.y = __float2half(T1 - T0);
        tab[5 * WPAD + w] = __uint_as_float(*reinterpret_cast<unsigned*>(&h2));
    }
}

struct f4u { float v[4]; };  // 4B-aligned vec4 store (rows start at l*2101 floats)

__device__ __forceinline__ float vget(const float4& v, int j) {
    return j == 0 ? v.x : (j == 1 ? v.y : (j == 2 ? v.z : v.w));
}

template<bool USE_TAB>
__global__ __launch_bounds__(192) void prospect_kernel(
    const float* __restrict__ pN,   const float* __restrict__ pcab,
    const float* __restrict__ pcar, const float* __restrict__ pwater,
    const float* __restrict__ plma, const float* __restrict__ pcant,
    const float* __restrict__ pnr,
    const float* __restrict__ pkab, const float* __restrict__ pkcar,
    const float* __restrict__ pkant, const float* __restrict__ pkw,
    const float* __restrict__ pkm,
    const float* __restrict__ tab,
    float* __restrict__ out_r, float* __restrict__ out_t)
{
    __shared__ unsigned TT[TAB_N];
    if (USE_TAB) {
        const float* src = tab + 5 * WPAD;
        for (int i = threadIdx.x; i < TAB_N; i += 192)
            TT[i] = __float_as_uint(src[i]);
        __syncthreads();
    }

    const int q  = blockIdx.x * 192 + threadIdx.x;   // quad-of-wavelengths in leaf
    const int w0 = q * 4;
    if (w0 >= W_LAMBDA) return;
    const bool full = (w0 + 4 <= W_LAMBDA);

    const int l = blockIdx.y;          // leaf: wave-uniform -> SGPR trait loads
    const float Nl   = pN[l];
    const float invN = rcpf(Nl);
    const float Nm1  = Nl - 1.0f;
    const float cabl = pcab[l], carl = pcar[l], cantl = pcant[l];
    const float watl = pwater[l], lmal = plma[l];

    float4 vkab, vkcar, vkant, vkw, vkm;
    if (full) {
        vkab  = *(const float4*)(pkab  + w0);
        vkcar = *(const float4*)(pkcar + w0);
        vkant = *(const float4*)(pkant + w0);
        vkw   = *(const float4*)(pkw   + w0);
        vkm   = *(const float4*)(pkm   + w0);
    } else {
        #pragma unroll
        for (int j = 0; j < 4; ++j) {
            int w = min(w0 + j, W_LAMBDA - 1);
            ((float*)&vkab)[j]  = pkab[w];
            ((float*)&vkcar)[j] = pkcar[w];
            ((float*)&vkant)[j] = pkant[w];
            ((float*)&vkw)[j]   = pkw[w];
            ((float*)&vkm)[j]   = pkm[w];
        }
    }
    float4 t0, t1, t2, t3, t4;
    if (USE_TAB) {
        t0 = *(const float4*)(tab + 0 * WPAD + w0);
        t1 = *(const float4*)(tab + 1 * WPAD + w0);
        t2 = *(const float4*)(tab + 2 * WPAD + w0);
        t3 = *(const float4*)(tab + 3 * WPAD + w0);
        t4 = *(const float4*)(tab + 4 * WPAD + w0);
    } else {
        #pragma unroll
        for (int j = 0; j < 4; ++j) {
            int w = min(w0 + j, W_LAMBDA - 1);
            float n    = pnr[w];
            float talf = getav_dev(SA2_40, false, n);
            float t12  = getav_dev(1.0f,   true,  n);
            float t21  = t12 * rcpf(n * n);
            float r21  = 1.0f - t21;
            ((float*)&t0)[j] = talf * t21;
            ((float*)&t1)[j] = 1.0f - talf;
            ((float*)&t2)[j] = t12 * t21;
            ((float*)&t3)[j] = 1.0f - t12;
            ((float*)&t4)[j] = r21;
        }
    }

    float rf[4], tr[4];
    #pragma unroll
    for (int j = 0; j < 4; ++j) {
        const float c0 = vget(t0, j), c1 = vget(t1, j), c2 = vget(t2, j);
        const float c3 = vget(t3, j), c4 = vget(t4, j);

        // absorption coefficient
        float k = (cabl * vget(vkab, j) + carl * vget(vkcar, j) + cantl * vget(vkant, j)
                 + watl * vget(vkw, j) + lmal * vget(vkm, j)) * invN;
        k = fmaxf(k, 1e-4f);

        float tau;
        if (USE_TAB) {
            // tau(k): one 4B LDS gather (packed half2 {T, dT}) + lerp
            float kc = fminf(k, 15.9f);
            unsigned bits = __float_as_uint(kc);
            int idx = (int)(bits >> 17) - 7232;          // 113<<6
            float frac = (float)(bits & 0x1FFFFu) * (1.0f / 131072.0f);
            unsigned u = TT[idx];
            __half2 h2 = *reinterpret_cast<const __half2*>(&u);
            float2 Tf = __half22float2(h2);
            tau = fmaf(frac, Tf.y, Tf.x);
        } else {
            tau = tau_exact(k);
        }

        // one-layer R/T; denom from (r21*tau)^2
        float r21t = c4 * tau;
        float rd   = rcpf(fmaf(-r21t, r21t, 1.0f));  // 1/(1 - r21^2 tau^2)
        float trd  = tau * rd;
        float Ta   = c0 * trd;                       // talf*t21 * tau / denom
        float tt   = c2 * trd;                       // t12*t21  * tau / denom
        float Ra   = fmaf(r21t, Ta, c1);
        float rr   = fmaf(r21t, tt, c3);

        // Stokes N-1 layers (den2*den3 merged into M)
        float rpt  = rr + tt;
        float rmt  = rr - tt;
        bool  mask = (rpt >= 1.0f);
        float Dsq  = fmaf(-rmt, rmt, 1.0f) * fmaf(-rpt, rpt, 1.0f);
        float D    = sqrtf_fast(mask ? 1.0f : Dsq);
        float rq   = rpt * rmt;                      // r^2 - t^2
        float s1   = 1.0f + D;
        float rp2  = rcpf((rr * tt) * 4.0f);         // pair-reciprocal 1/(2r),1/(2t)
        float aa   = (s1 + rq) * (rp2 * (tt + tt));
        float bb   = (s1 - rq) * (rp2 * (rr + rr));
        float bsafe = mask ? 1.0f : bb;
        float bnm1 = exp2f_fast(Nm1 * log2f_fast(bsafe));   // b^(N-1)
        float bn2  = bnm1 * bnm1;
        float a2   = aa * aa;
        float den2 = fmaf(a2, bn2, -1.0f);           // a^2 b^{2n} - 1
        float bn2m1 = bn2 - 1.0f;
        float M    = fmaf(-aa * rr, bn2m1, den2);    // den2 - a r (b^{2n}-1) = den2*den3
        float invM = rcpf(M);
        float TaM  = Ta * invM;
        float tranj = TaM * bnm1 * (a2 - 1.0f);      // Ta*Tsub/den3
        float reflj = fmaf(TaM * tt * aa, bn2m1, Ra);// Ra + Ta*Rsub*t/den3

        if (__any((int)mask)) {                      // thick-leaf branch (rare/never)
            float Talt = tt * rcpf(fmaf(Nm1, 1.0f - tt, tt));
            float Rsm  = 1.0f - Talt;
            float g    = Ta * rcpf(fmaf(-Rsm, rr, 1.0f));
            if (mask) { tranj = g * Talt; reflj = fmaf(g * Rsm, tt, Ra); }
        }

        tr[j] = tranj;
        rf[j] = reflj;
    }

    const unsigned base = (unsigned)l * W_LAMBDA + (unsigned)w0;
    if (full) {
        f4u fr; f4u ft;
        #pragma unroll
        for (int j = 0; j < 4; ++j) { fr.v[j] = rf[j]; ft.v[j] = tr[j]; }
        *reinterpret_cast<f4u*>(out_r + base) = fr;
        *reinterpret_cast<f4u*>(out_t + base) = ft;
    } else {
        out_r[base] = rf[0];
        out_t[base] = tr[0];
    }
}

extern "C" void kernel_launch(void* const* d_in, const int* in_sizes, int n_in,
                              void* d_out, int out_size, void* d_ws, size_t ws_size,
                              hipStream_t stream) {
    const float* pN     = (const float*)d_in[0];
    const float* pcab   = (const float*)d_in[1];
    const float* pcar   = (const float*)d_in[2];
    const float* pwater = (const float*)d_in[3];
    const float* plma   = (const float*)d_in[4];
    const float* pcant  = (const float*)d_in[5];
    const float* pnr    = (const float*)d_in[6];
    const float* pkab   = (const float*)d_in[7];
    const float* pkcar  = (const float*)d_in[8];
    const float* pkant  = (const float*)d_in[9];
    const float* pkw    = (const float*)d_in[10];
    const float* pkm    = (const float*)d_in[11];
    float* out_r = (float*)d_out;
    float* out_t = out_r + (size_t)L_LEAVES * W_LAMBDA;

    const int nquads = (W_LAMBDA + 3) / 4;                 // 526
    dim3 grid((nquads + 191) / 192, L_LEAVES);             // (3, 8192)
    dim3 block(192);

    const size_t tab_bytes = (5 * WPAD + TAB_N) * sizeof(float);
    if (ws_size >= tab_bytes) {
        float* tabp = (float*)d_ws;
        precompute_kernel<<<(WPAD + 63) / 64, 64, 0, stream>>>(pnr, tabp);
        prospect_kernel<true><<<grid, block, 0, stream>>>(
            pN, pcab, pcar, pwater, plma, pcant, pnr,
            pkab, pkcar, pkant, pkw, pkm, (const float*)tabp, out_r, out_t);
    } else {
        prospect_kernel<false><<<grid, block, 0, stream>>>(
            pN, pcab, pcar, pwater, plma, pcant, pnr,
            pkab, pkcar, pkant, pkw, pkm, nullptr, out_r, out_t);
    }
}

// Round 11
// 52.824 us; speedup vs baseline: 1.0971x; 1.0451x over previous
//
#include <hip/hip_runtime.h>
#include <hip/hip_fp16.h>

#define L_LEAVES 8192
#define W_LAMBDA 2101
#define WPAD     2104              // padded table stride (16B-aligned rows)
#define TAB_N    1153              // tau table: 18 octaves * 64 + 1 fencepost (k in [2^-14, 16))
#define SA2_40   0.41317591116653485f
#define LOG2E_F  1.4426950408889634f
#define LN2_F    0.6931471805599453f

typedef float v2f __attribute__((ext_vector_type(2)));

__device__ __forceinline__ float rcpf(float x)  { return __builtin_amdgcn_rcpf(x); }
__device__ __forceinline__ float log2f_fast(float x) { return __builtin_amdgcn_logf(x); }
__device__ __forceinline__ float exp2f_fast(float x) { return __builtin_amdgcn_exp2f(x); }
__device__ __forceinline__ float sqrtf_fast(float x) { return __builtin_amdgcn_sqrtf(x); }
__device__ __forceinline__ v2f v2(float a, float b) { v2f r; r.x = a; r.y = b; return r; }

// ---- transmissivity of a dielectric plane (Stern / Allen) ----
// fast-intrinsic version (precompute only; ~1e-6 rel accuracy vs 2e-2 tol)
__device__ __forceinline__ float getav_dev(float sa2, bool is90, float nr) {
    float n2  = nr * nr;
    float npx = n2 + 1.0f;
    float nm  = n2 - 1.0f;
    float a   = (nr + 1.0f) * (nr + 1.0f) * 0.5f;
    float k   = -(n2 - 1.0f) * (n2 - 1.0f) * 0.25f;
    float b2  = sa2 - npx * 0.5f;
    float b1  = is90 ? 0.0f : sqrtf_fast(b2 * b2 + k);
    float b   = b1 - b2;
    float k2  = k * k;
    float ib  = rcpf(b), ia = rcpf(a);
    float ts  = k2 * (1.0f/6.0f) * (ib*ib*ib) + k * ib - b * 0.5f
              - (k2 * (1.0f/6.0f) * (ia*ia*ia) + k * ia - a * 0.5f);
    float inpx = rcpf(npx);
    float tp1 = -2.0f * n2 * (b - a) * (inpx * inpx);
    float nm2 = nm * nm;
    float inm2 = rcpf(nm2);
    float tp2 = -2.0f * n2 * npx * (LN2_F * log2f_fast(b * ia)) * inm2;
    float tp3 = n2 * (ib - ia) * 0.5f;
    float n22 = n2 * n2;
    float inpx3 = inpx * inpx * inpx;
    float npax_a = 2.0f * npx * a - nm2;
    float npx_b  = 2.0f * npx * b - nm2;
    float tp4 = 16.0f * n22 * (n22 + 1.0f) * (LN2_F * log2f_fast(npx_b * rcpf(npax_a))) * inpx3 * inm2;
    float tp5 = 16.0f * n2 * n2 * n2 * (rcpf(npx_b) - rcpf(npax_a)) * inpx3;
    float tp  = tp1 + tp2 + tp3 + tp4 + tp5;
    return (ts + tp) * rcpf(2.0f * sa2);
}

// tau(k) for table construction (fast intrinsics; abs err ~1e-6)
__device__ __forceinline__ float tau_exact(float k) {
    float ek = exp2f_fast(-k * LOG2E_F);
    float e1;
    if (k <= 1.0f) {
        float poly = fmaf(fmaf(fmaf(fmaf(fmaf(0.00107857f, k, -0.00976004f), k, 0.05519968f),
                        k, -0.24991055f), k, 0.99999193f), k, -0.57721566f);
        e1 = fmaf(-LN2_F, log2f_fast(k), poly);
    } else {
        float pn = fmaf(fmaf(fmaf(k + 8.5733287401f, k, 18.0590169730f),
                       k, 8.6347608925f), k, 0.2677737343f);
        float pd = fmaf(fmaf(fmaf(k + 9.5733223454f, k, 25.6329561486f),
                       k, 21.0996530827f), k, 3.9584969228f);
        e1 = ek * rcpf(k) * (pn * rcpf(pd));
    }
    return fmaf(k * k, e1, (1.0f - k) * ek);
}

__device__ __forceinline__ float bin_k(int w) {
    unsigned e = (unsigned)w >> 6, m = (unsigned)w & 63u;
    return __uint_as_float(((113u + e) << 23) | (m << 17));
}

// d_ws layout: rows 0..4 (WPAD floats): talf*t21, ralf, t12*t21, r12, r21
// then TAB_N packed half2 {tau_i, tau_{i+1}-tau_i} (one 4B word each) at 5*WPAD
__global__ void precompute_kernel(const float* __restrict__ nr, float* __restrict__ tab) {
    int w = blockIdx.x * blockDim.x + threadIdx.x;
    if (w < WPAD) {                           // pad filled with clones of last column
        int ws = min(w, W_LAMBDA - 1);
        float n    = nr[ws];
        float talf = getav_dev(SA2_40, false, n);
        float t12  = getav_dev(1.0f,   true,  n);
        float t21  = t12 * rcpf(n * n);
        float r21  = 1.0f - t21;
        tab[0 * WPAD + w] = talf * t21;
        tab[1 * WPAD + w] = 1.0f - talf;
        tab[2 * WPAD + w] = t12 * t21;
        tab[3 * WPAD + w] = 1.0f - t12;
        tab[4 * WPAD + w] = r21;
    }
    if (w < TAB_N) {
        float T0 = tau_exact(bin_k(w));
        float T1 = tau_exact(bin_k(w + 1));
        __half2 h2;
        h2.x = __float2half(T0);
        h2.y = __float2half(T1 - T0);
        tab[5 * WPAD + w] = __uint_as_float(*reinterpret_cast<unsigned*>(&h2));
    }
}

struct f4u { float v[4]; };  // 4B-aligned vec4 store (rows start at l*2101 floats)

template<bool USE_TAB>
__global__ __launch_bounds__(192) void prospect_kernel(
    const float* __restrict__ pN,   const float* __restrict__ pcab,
    const float* __restrict__ pcar, const float* __restrict__ pwater,
    const float* __restrict__ plma, const float* __restrict__ pcant,
    const float* __restrict__ pnr,
    const float* __restrict__ pkab, const float* __restrict__ pkcar,
    const float* __restrict__ pkant, const float* __restrict__ pkw,
    const float* __restrict__ pkm,
    const float* __restrict__ tab,
    float* __restrict__ out_r, float* __restrict__ out_t)
{
    __shared__ unsigned TT[TAB_N];
    if (USE_TAB) {
        const float* src = tab + 5 * WPAD;
        for (int i = threadIdx.x; i < TAB_N; i += 192)
            TT[i] = __float_as_uint(src[i]);
        __syncthreads();
    }

    const int q  = blockIdx.x * 192 + threadIdx.x;   // quad-of-wavelengths in leaf
    const int w0 = q * 4;
    if (w0 >= W_LAMBDA) return;
    const bool full = (w0 + 4 <= W_LAMBDA);

    const int l = blockIdx.y;          // leaf: wave-uniform -> SGPR trait loads
    const float Nl   = pN[l];
    const float invN = rcpf(Nl);
    const float Nm1  = Nl - 1.0f;
    const float cabl = pcab[l], carl = pcar[l], cantl = pcant[l];
    const float watl = pwater[l], lmal = plma[l];

    float4 vkab, vkcar, vkant, vkw, vkm;
    if (full) {
        vkab  = *(const float4*)(pkab  + w0);
        vkcar = *(const float4*)(pkcar + w0);
        vkant = *(const float4*)(pkant + w0);
        vkw   = *(const float4*)(pkw   + w0);
        vkm   = *(const float4*)(pkm   + w0);
    } else {
        #pragma unroll
        for (int j = 0; j < 4; ++j) {
            int w = min(w0 + j, W_LAMBDA - 1);
            ((float*)&vkab)[j]  = pkab[w];
            ((float*)&vkcar)[j] = pkcar[w];
            ((float*)&vkant)[j] = pkant[w];
            ((float*)&vkw)[j]   = pkw[w];
            ((float*)&vkm)[j]   = pkm[w];
        }
    }
    float4 t0, t1, t2, t3, t4;
    if (USE_TAB) {
        t0 = *(const float4*)(tab + 0 * WPAD + w0);
        t1 = *(const float4*)(tab + 1 * WPAD + w0);
        t2 = *(const float4*)(tab + 2 * WPAD + w0);
        t3 = *(const float4*)(tab + 3 * WPAD + w0);
        t4 = *(const float4*)(tab + 4 * WPAD + w0);
    } else {
        #pragma unroll
        for (int j = 0; j < 4; ++j) {
            int w = min(w0 + j, W_LAMBDA - 1);
            float n    = pnr[w];
            float talf = getav_dev(SA2_40, false, n);
            float t12  = getav_dev(1.0f,   true,  n);
            float t21  = t12 * rcpf(n * n);
            float r21  = 1.0f - t21;
            ((float*)&t0)[j] = talf * t21;
            ((float*)&t1)[j] = 1.0f - talf;
            ((float*)&t2)[j] = t12 * t21;
            ((float*)&t3)[j] = 1.0f - t12;
            ((float*)&t4)[j] = r21;
        }
    }

    float rf[4], tr[4];
    #pragma unroll
    for (int p = 0; p < 2; ++p) {
        // pair components j = 2p, 2p+1 — all chain math as <2 x float> (v_pk_* ops)
        const v2f c0 = p ? v2(t0.z, t0.w) : v2(t0.x, t0.y);
        const v2f c1 = p ? v2(t1.z, t1.w) : v2(t1.x, t1.y);
        const v2f c2 = p ? v2(t2.z, t2.w) : v2(t2.x, t2.y);
        const v2f c3 = p ? v2(t3.z, t3.w) : v2(t3.x, t3.y);
        const v2f c4 = p ? v2(t4.z, t4.w) : v2(t4.x, t4.y);
        const v2f ab = p ? v2(vkab.z, vkab.w) : v2(vkab.x, vkab.y);
        const v2f cr = p ? v2(vkcar.z, vkcar.w) : v2(vkcar.x, vkcar.y);
        const v2f an = p ? v2(vkant.z, vkant.w) : v2(vkant.x, vkant.y);
        const v2f wt = p ? v2(vkw.z, vkw.w) : v2(vkw.x, vkw.y);
        const v2f lm = p ? v2(vkm.z, vkm.w) : v2(vkm.x, vkm.y);

        // absorption coefficient
        v2f k = (cabl * ab + carl * cr + cantl * an + watl * wt + lmal * lm) * invN;
        k = __builtin_elementwise_max(k, (v2f)1e-4f);

        v2f tau;
        if (USE_TAB) {
            v2f kc = __builtin_elementwise_min(k, (v2f)15.9f);
            unsigned b0 = __float_as_uint(kc.x), b1 = __float_as_uint(kc.y);
            unsigned u0 = TT[(int)(b0 >> 17) - 7232];
            unsigned u1 = TT[(int)(b1 >> 17) - 7232];
            float2 Tf0 = __half22float2(*reinterpret_cast<const __half2*>(&u0));
            float2 Tf1 = __half22float2(*reinterpret_cast<const __half2*>(&u1));
            v2f frac = v2((float)(b0 & 0x1FFFFu), (float)(b1 & 0x1FFFFu)) * (1.0f / 131072.0f);
            tau = frac * v2(Tf0.y, Tf1.y) + v2(Tf0.x, Tf1.x);
        } else {
            tau = v2(tau_exact(k.x), tau_exact(k.y));
        }

        // one-layer R/T
        v2f r21t = c4 * tau;
        v2f d1   = 1.0f - r21t * r21t;
        v2f rd   = v2(rcpf(d1.x), rcpf(d1.y));
        v2f trd  = tau * rd;
        v2f Ta   = c0 * trd;
        v2f tt   = c2 * trd;
        v2f Ra   = r21t * Ta + c1;
        v2f rr   = r21t * tt + c3;

        // Stokes N-1 layers (den2*den3 merged into M)
        v2f rpt = rr + tt;
        v2f rmt = rr - tt;
        bool m0 = (rpt.x >= 1.0f), m1 = (rpt.y >= 1.0f);
        v2f Dsq = (1.0f - rmt * rmt) * (1.0f - rpt * rpt);
        v2f D   = v2(sqrtf_fast(m0 ? 1.0f : Dsq.x), sqrtf_fast(m1 ? 1.0f : Dsq.y));
        v2f rq  = rpt * rmt;
        v2f s1  = 1.0f + D;
        v2f prod = (rr * tt) * 4.0f;
        v2f rp2  = v2(rcpf(prod.x), rcpf(prod.y));
        v2f aa   = (s1 + rq) * (rp2 * (tt + tt));
        v2f bb   = (s1 - rq) * (rp2 * (rr + rr));
        v2f lg   = v2(log2f_fast(m0 ? 1.0f : bb.x), log2f_fast(m1 ? 1.0f : bb.y));
        v2f ex   = Nm1 * lg;
        v2f bnm1 = v2(exp2f_fast(ex.x), exp2f_fast(ex.y));
        v2f bn2  = bnm1 * bnm1;
        v2f a2   = aa * aa;
        v2f den2 = a2 * bn2 - 1.0f;
        v2f bn2m1 = bn2 - 1.0f;
        v2f M    = den2 - (aa * rr) * bn2m1;
        v2f invM = v2(rcpf(M.x), rcpf(M.y));
        v2f TaM  = Ta * invM;
        v2f tranv = TaM * bnm1 * (a2 - 1.0f);
        v2f reflv = (TaM * tt * aa) * bn2m1 + Ra;

        if (__any((int)(m0 || m1))) {            // thick-leaf fixup (rare/never)
            #pragma unroll
            for (int c = 0; c < 2; ++c) {
                bool m = c ? m1 : m0;
                if (m) {
                    float ttc = c ? tt.y : tt.x, rrc = c ? rr.y : rr.x;
                    float Tac = c ? Ta.y : Ta.x, Rac = c ? Ra.y : Ra.x;
                    float Talt = ttc * rcpf(fmaf(Nm1, 1.0f - ttc, ttc));
                    float Rsm  = 1.0f - Talt;
                    float g    = Tac * rcpf(fmaf(-Rsm, rrc, 1.0f));
                    if (c) { tranv.y = g * Talt; reflv.y = fmaf(g * Rsm, ttc, Rac); }
                    else   { tranv.x = g * Talt; reflv.x = fmaf(g * Rsm, ttc, Rac); }
                }
            }
        }

        tr[2 * p]     = tranv.x;
        tr[2 * p + 1] = tranv.y;
        rf[2 * p]     = reflv.x;
        rf[2 * p + 1] = reflv.y;
    }

    const unsigned base = (unsigned)l * W_LAMBDA + (unsigned)w0;
    if (full) {
        f4u fr; f4u ft;
        #pragma unroll
        for (int j = 0; j < 4; ++j) { fr.v[j] = rf[j]; ft.v[j] = tr[j]; }
        *reinterpret_cast<f4u*>(out_r + base) = fr;
        *reinterpret_cast<f4u*>(out_t + base) = ft;
    } else {
        out_r[base] = rf[0];
        out_t[base] = tr[0];
    }
}

extern "C" void kernel_launch(void* const* d_in, const int* in_sizes, int n_in,
                              void* d_out, int out_size, void* d_ws, size_t ws_size,
                              hipStream_t stream) {
    const float* pN     = (const float*)d_in[0];
    const float* pcab   = (const float*)d_in[1];
    const float* pcar   = (const float*)d_in[2];
    const float* pwater = (const float*)d_in[3];
    const float* plma   = (const float*)d_in[4];
    const float* pcant  = (const float*)d_in[5];
    const float* pnr    = (const float*)d_in[6];
    const float* pkab   = (const float*)d_in[7];
    const float* pkcar  = (const float*)d_in[8];
    const float* pkant  = (const float*)d_in[9];
    const float* pkw    = (const float*)d_in[10];
    const float* pkm    = (const float*)d_in[11];
    float* out_r = (float*)d_out;
    float* out_t = out_r + (size_t)L_LEAVES * W_LAMBDA;

    const int nquads = (W_LAMBDA + 3) / 4;                 // 526
    dim3 grid((nquads + 191) / 192, L_LEAVES);             // (3, 8192)
    dim3 block(192);

    const size_t tab_bytes = (5 * WPAD + TAB_N) * sizeof(float);
    if (ws_size >= tab_bytes) {
        float* tabp = (float*)d_ws;
        precompute_kernel<<<(WPAD + 63) / 64, 64, 0, stream>>>(pnr, tabp);
        prospect_kernel<true><<<grid, block, 0, stream>>>(
            pN, pcab, pcar, pwater, plma, pcant, pnr,
            pkab, pkcar, pkant, pkw, pkm, (const float*)tabp, out_r, out_t);
    } else {
        prospect_kernel<false><<<grid, block, 0, stream>>>(
            pN, pcab, pcar, pwater, plma, pcant, pnr,
            pkab, pkcar, pkant, pkw, pkm, nullptr, out_r, out_t);
    }
}

// Round 12
// 51.091 us; speedup vs baseline: 1.1343x; 1.0339x over previous
//
#include <hip/hip_runtime.h>
#include <hip/hip_fp16.h>

#define L_LEAVES 8192
#define W_LAMBDA 2101
#define WPAD     2104              // padded table stride (16B-aligned rows)
#define TAB_N    1153              // tau table: 18 octaves * 64 + 1 fencepost (k in [2^-14, 16))
#define SA2_40   0.41317591116653485f
#define LOG2E_F  1.4426950408889634f
#define LN2_F    0.6931471805599453f

typedef float v2f __attribute__((ext_vector_type(2)));

__device__ __forceinline__ float rcpf(float x)  { return __builtin_amdgcn_rcpf(x); }
__device__ __forceinline__ float log2f_fast(float x) { return __builtin_amdgcn_logf(x); }
__device__ __forceinline__ float exp2f_fast(float x) { return __builtin_amdgcn_exp2f(x); }
__device__ __forceinline__ float sqrtf_fast(float x) { return __builtin_amdgcn_sqrtf(x); }
__device__ __forceinline__ v2f v2(float a, float b) { v2f r; r.x = a; r.y = b; return r; }

// ---- transmissivity of a dielectric plane (Stern / Allen) ----
// fast-intrinsic version (precompute only; ~1e-6 rel accuracy vs 2e-2 tol)
__device__ __forceinline__ float getav_dev(float sa2, bool is90, float nr) {
    float n2  = nr * nr;
    float npx = n2 + 1.0f;
    float nm  = n2 - 1.0f;
    float a   = (nr + 1.0f) * (nr + 1.0f) * 0.5f;
    float k   = -(n2 - 1.0f) * (n2 - 1.0f) * 0.25f;
    float b2  = sa2 - npx * 0.5f;
    float b1  = is90 ? 0.0f : sqrtf_fast(b2 * b2 + k);
    float b   = b1 - b2;
    float k2  = k * k;
    float ib  = rcpf(b), ia = rcpf(a);
    float ts  = k2 * (1.0f/6.0f) * (ib*ib*ib) + k * ib - b * 0.5f
              - (k2 * (1.0f/6.0f) * (ia*ia*ia) + k * ia - a * 0.5f);
    float inpx = rcpf(npx);
    float tp1 = -2.0f * n2 * (b - a) * (inpx * inpx);
    float nm2 = nm * nm;
    float inm2 = rcpf(nm2);
    float tp2 = -2.0f * n2 * npx * (LN2_F * log2f_fast(b * ia)) * inm2;
    float tp3 = n2 * (ib - ia) * 0.5f;
    float n22 = n2 * n2;
    float inpx3 = inpx * inpx * inpx;
    float npax_a = 2.0f * npx * a - nm2;
    float npx_b  = 2.0f * npx * b - nm2;
    float tp4 = 16.0f * n22 * (n22 + 1.0f) * (LN2_F * log2f_fast(npx_b * rcpf(npax_a))) * inpx3 * inm2;
    float tp5 = 16.0f * n2 * n2 * n2 * (rcpf(npx_b) - rcpf(npax_a)) * inpx3;
    float tp  = tp1 + tp2 + tp3 + tp4 + tp5;
    return (ts + tp) * rcpf(2.0f * sa2);
}

// tau(k) for table construction (fast intrinsics; abs err ~1e-6)
__device__ __forceinline__ float tau_exact(float k) {
    float ek = exp2f_fast(-k * LOG2E_F);
    float e1;
    if (k <= 1.0f) {
        float poly = fmaf(fmaf(fmaf(fmaf(fmaf(0.00107857f, k, -0.00976004f), k, 0.05519968f),
                        k, -0.24991055f), k, 0.99999193f), k, -0.57721566f);
        e1 = fmaf(-LN2_F, log2f_fast(k), poly);
    } else {
        float pn = fmaf(fmaf(fmaf(k + 8.5733287401f, k, 18.0590169730f),
                       k, 8.6347608925f), k, 0.2677737343f);
        float pd = fmaf(fmaf(fmaf(k + 9.5733223454f, k, 25.6329561486f),
                       k, 21.0996530827f), k, 3.9584969228f);
        e1 = ek * rcpf(k) * (pn * rcpf(pd));
    }
    return fmaf(k * k, e1, (1.0f - k) * ek);
}

__device__ __forceinline__ float bin_k(int w) {
    unsigned e = (unsigned)w >> 6, m = (unsigned)w & 63u;
    return __uint_as_float(((113u + e) << 23) | (m << 17));
}

// d_ws layout: rows 0..4 (WPAD floats): talf*t21, ralf, t12*t21, r12, r21
// then TAB_N packed half2 {tau_i, tau_{i+1}-tau_i} (one 4B word each) at 5*WPAD
__global__ void precompute_kernel(const float* __restrict__ nr, float* __restrict__ tab) {
    int w = blockIdx.x * blockDim.x + threadIdx.x;
    if (w < WPAD) {                           // pad filled with clones of last column
        int ws = min(w, W_LAMBDA - 1);
        float n    = nr[ws];
        float talf = getav_dev(SA2_40, false, n);
        float t12  = getav_dev(1.0f,   true,  n);
        float t21  = t12 * rcpf(n * n);
        float r21  = 1.0f - t21;
        tab[0 * WPAD + w] = talf * t21;
        tab[1 * WPAD + w] = 1.0f - talf;
        tab[2 * WPAD + w] = t12 * t21;
        tab[3 * WPAD + w] = 1.0f - t12;
        tab[4 * WPAD + w] = r21;
    }
    if (w < TAB_N) {
        float T0 = tau_exact(bin_k(w));
        float T1 = tau_exact(bin_k(w + 1));
        __half2 h2;
        h2.x = __float2half(T0);
        h2.y = __float2half(T1 - T0);
        tab[5 * WPAD + w] = __uint_as_float(*reinterpret_cast<unsigned*>(&h2));
    }
}

// scalar single-point Stokes pipeline (tail wave)
__device__ __forceinline__ void stokes_point(float tau, float c0, float c1, float c2,
                                             float c3, float c4, float Nm1,
                                             float& refl, float& tran) {
    float r21t = c4 * tau;
    float rd   = rcpf(fmaf(-r21t, r21t, 1.0f));
    float trd  = tau * rd;
    float Ta   = c0 * trd;
    float tt   = c2 * trd;
    float Ra   = fmaf(r21t, Ta, c1);
    float rr   = fmaf(r21t, tt, c3);
    float rpt  = rr + tt;
    float rmt  = rr - tt;
    bool  mask = (rpt >= 1.0f);
    float Dsq  = fmaf(-rmt, rmt, 1.0f) * fmaf(-rpt, rpt, 1.0f);
    float D    = sqrtf_fast(mask ? 1.0f : Dsq);
    float rq   = rpt * rmt;
    float s1   = 1.0f + D;
    float rp2  = rcpf((rr * tt) * 4.0f);
    float aa   = (s1 + rq) * (rp2 * (tt + tt));
    float bb   = (s1 - rq) * (rp2 * (rr + rr));
    float bnm1 = exp2f_fast(Nm1 * log2f_fast(mask ? 1.0f : bb));
    float bn2  = bnm1 * bnm1;
    float a2   = aa * aa;
    float den2 = fmaf(a2, bn2, -1.0f);
    float bn2m1 = bn2 - 1.0f;
    float M    = fmaf(-aa * rr, bn2m1, den2);
    float invM = rcpf(M);
    float TaM  = Ta * invM;
    tran = TaM * bnm1 * (a2 - 1.0f);
    refl = fmaf(TaM * tt * aa, bn2m1, Ra);
    if (mask) {
        float Talt = tt * rcpf(fmaf(Nm1, 1.0f - tt, tt));
        float Rsm  = 1.0f - Talt;
        float g    = Ta * rcpf(fmaf(-Rsm, rr, 1.0f));
        tran = g * Talt;
        refl = fmaf(g * Rsm, tt, Ra);
    }
}

struct f4u { float v[4]; };  // 4B-aligned vec4 store (rows start at l*2101 floats)

template<bool USE_TAB>
__global__ __launch_bounds__(576) void prospect_kernel(
    const float* __restrict__ pN,   const float* __restrict__ pcab,
    const float* __restrict__ pcar, const float* __restrict__ pwater,
    const float* __restrict__ plma, const float* __restrict__ pcant,
    const float* __restrict__ pnr,
    const float* __restrict__ pkab, const float* __restrict__ pkcar,
    const float* __restrict__ pkant, const float* __restrict__ pkw,
    const float* __restrict__ pkm,
    const float* __restrict__ tab,
    float* __restrict__ out_r, float* __restrict__ out_t)
{
    __shared__ unsigned TT[TAB_N];
    if (USE_TAB) {
        const float* src = tab + 5 * WPAD;
        for (int i = threadIdx.x; i < TAB_N; i += 576)
            TT[i] = __float_as_uint(src[i]);
        __syncthreads();
    }

    const int l = blockIdx.x;          // one block per leaf: wave-uniform SGPR traits
    const float Nl   = pN[l];
    const float invN = rcpf(Nl);
    const float Nm1  = Nl - 1.0f;
    const float cabl = pcab[l], carl = pcar[l], cantl = pcant[l];
    const float watl = pwater[l], lmal = plma[l];
    const int tid = threadIdx.x;
    const unsigned rowbase = (unsigned)l * W_LAMBDA;

    if (tid < 512) {
        // ---- main path: waves 0-7, 4 wavelengths each, NO bounds checks ----
        const int w0 = tid * 4;        // 0..2044; w0+4 <= 2048 <= W_LAMBDA always

        float4 vkab  = *(const float4*)(pkab  + w0);
        float4 vkcar = *(const float4*)(pkcar + w0);
        float4 vkant = *(const float4*)(pkant + w0);
        float4 vkw   = *(const float4*)(pkw   + w0);
        float4 vkm   = *(const float4*)(pkm   + w0);
        float4 t0, t1, t2, t3, t4;
        if (USE_TAB) {
            t0 = *(const float4*)(tab + 0 * WPAD + w0);
            t1 = *(const float4*)(tab + 1 * WPAD + w0);
            t2 = *(const float4*)(tab + 2 * WPAD + w0);
            t3 = *(const float4*)(tab + 3 * WPAD + w0);
            t4 = *(const float4*)(tab + 4 * WPAD + w0);
        } else {
            #pragma unroll
            for (int j = 0; j < 4; ++j) {
                int w = w0 + j;
                float n    = pnr[w];
                float talf = getav_dev(SA2_40, false, n);
                float t12  = getav_dev(1.0f,   true,  n);
                float t21  = t12 * rcpf(n * n);
                float r21  = 1.0f - t21;
                ((float*)&t0)[j] = talf * t21;
                ((float*)&t1)[j] = 1.0f - talf;
                ((float*)&t2)[j] = t12 * t21;
                ((float*)&t3)[j] = 1.0f - t12;
                ((float*)&t4)[j] = r21;
            }
        }

        float rf[4], tr[4];
        #pragma unroll
        for (int p = 0; p < 2; ++p) {
            const v2f c0 = p ? v2(t0.z, t0.w) : v2(t0.x, t0.y);
            const v2f c1 = p ? v2(t1.z, t1.w) : v2(t1.x, t1.y);
            const v2f c2 = p ? v2(t2.z, t2.w) : v2(t2.x, t2.y);
            const v2f c3 = p ? v2(t3.z, t3.w) : v2(t3.x, t3.y);
            const v2f c4 = p ? v2(t4.z, t4.w) : v2(t4.x, t4.y);
            const v2f ab = p ? v2(vkab.z, vkab.w) : v2(vkab.x, vkab.y);
            const v2f cr = p ? v2(vkcar.z, vkcar.w) : v2(vkcar.x, vkcar.y);
            const v2f an = p ? v2(vkant.z, vkant.w) : v2(vkant.x, vkant.y);
            const v2f wt = p ? v2(vkw.z, vkw.w) : v2(vkw.x, vkw.y);
            const v2f lm = p ? v2(vkm.z, vkm.w) : v2(vkm.x, vkm.y);

            v2f k = (cabl * ab + carl * cr + cantl * an + watl * wt + lmal * lm) * invN;
            k = __builtin_elementwise_max(k, (v2f)1e-4f);

            v2f tau;
            if (USE_TAB) {
                v2f kc = __builtin_elementwise_min(k, (v2f)15.9f);
                unsigned b0 = __float_as_uint(kc.x), b1 = __float_as_uint(kc.y);
                unsigned u0 = TT[(int)(b0 >> 17) - 7232];
                unsigned u1 = TT[(int)(b1 >> 17) - 7232];
                float2 Tf0 = __half22float2(*reinterpret_cast<const __half2*>(&u0));
                float2 Tf1 = __half22float2(*reinterpret_cast<const __half2*>(&u1));
                v2f frac = v2((float)(b0 & 0x1FFFFu), (float)(b1 & 0x1FFFFu)) * (1.0f / 131072.0f);
                tau = frac * v2(Tf0.y, Tf1.y) + v2(Tf0.x, Tf1.x);
            } else {
                tau = v2(tau_exact(k.x), tau_exact(k.y));
            }

            v2f r21t = c4 * tau;
            v2f d1   = 1.0f - r21t * r21t;
            v2f rd   = v2(rcpf(d1.x), rcpf(d1.y));
            v2f trd  = tau * rd;
            v2f Ta   = c0 * trd;
            v2f tt   = c2 * trd;
            v2f Ra   = r21t * Ta + c1;
            v2f rr   = r21t * tt + c3;

            v2f rpt = rr + tt;
            v2f rmt = rr - tt;
            bool m0 = (rpt.x >= 1.0f), m1 = (rpt.y >= 1.0f);
            v2f Dsq = (1.0f - rmt * rmt) * (1.0f - rpt * rpt);
            v2f D   = v2(sqrtf_fast(m0 ? 1.0f : Dsq.x), sqrtf_fast(m1 ? 1.0f : Dsq.y));
            v2f rq  = rpt * rmt;
            v2f s1  = 1.0f + D;
            v2f prod = (rr * tt) * 4.0f;
            v2f rp2  = v2(rcpf(prod.x), rcpf(prod.y));
            v2f aa   = (s1 + rq) * (rp2 * (tt + tt));
            v2f bb   = (s1 - rq) * (rp2 * (rr + rr));
            v2f lg   = v2(log2f_fast(m0 ? 1.0f : bb.x), log2f_fast(m1 ? 1.0f : bb.y));
            v2f ex   = Nm1 * lg;
            v2f bnm1 = v2(exp2f_fast(ex.x), exp2f_fast(ex.y));
            v2f bn2  = bnm1 * bnm1;
            v2f a2   = aa * aa;
            v2f den2 = a2 * bn2 - 1.0f;
            v2f bn2m1 = bn2 - 1.0f;
            v2f M    = den2 - (aa * rr) * bn2m1;
            v2f invM = v2(rcpf(M.x), rcpf(M.y));
            v2f TaM  = Ta * invM;
            v2f tranv = TaM * bnm1 * (a2 - 1.0f);
            v2f reflv = (TaM * tt * aa) * bn2m1 + Ra;

            if (__any((int)(m0 || m1))) {            // thick-leaf fixup (rare/never)
                #pragma unroll
                for (int c = 0; c < 2; ++c) {
                    bool m = c ? m1 : m0;
                    if (m) {
                        float ttc = c ? tt.y : tt.x, rrc = c ? rr.y : rr.x;
                        float Tac = c ? Ta.y : Ta.x, Rac = c ? Ra.y : Ra.x;
                        float Talt = ttc * rcpf(fmaf(Nm1, 1.0f - ttc, ttc));
                        float Rsm  = 1.0f - Talt;
                        float g    = Tac * rcpf(fmaf(-Rsm, rrc, 1.0f));
                        if (c) { tranv.y = g * Talt; reflv.y = fmaf(g * Rsm, ttc, Rac); }
                        else   { tranv.x = g * Talt; reflv.x = fmaf(g * Rsm, ttc, Rac); }
                    }
                }
            }

            tr[2 * p]     = tranv.x;
            tr[2 * p + 1] = tranv.y;
            rf[2 * p]     = reflv.x;
            rf[2 * p + 1] = reflv.y;
        }

        const unsigned base = rowbase + (unsigned)w0;
        f4u fr; f4u ft;
        #pragma unroll
        for (int j = 0; j < 4; ++j) { fr.v[j] = rf[j]; ft.v[j] = tr[j]; }
        *reinterpret_cast<f4u*>(out_r + base) = fr;
        *reinterpret_cast<f4u*>(out_t + base) = ft;
    } else {
        // ---- tail path: wave 8, one wavelength per lane (w = 2048..2100) ----
        const int w = 2048 + (tid - 512);
        if (w < W_LAMBDA) {
            float k = (cabl * pkab[w] + carl * pkcar[w] + cantl * pkant[w]
                     + watl * pkw[w] + lmal * pkm[w]) * invN;
            k = fmaxf(k, 1e-4f);

            float c0, c1, c2, c3, c4;
            if (USE_TAB) {
                c0 = tab[0 * WPAD + w];
                c1 = tab[1 * WPAD + w];
                c2 = tab[2 * WPAD + w];
                c3 = tab[3 * WPAD + w];
                c4 = tab[4 * WPAD + w];
            } else {
                float n    = pnr[w];
                float talf = getav_dev(SA2_40, false, n);
                float t12  = getav_dev(1.0f,   true,  n);
                float t21  = t12 * rcpf(n * n);
                float r21  = 1.0f - t21;
                c0 = talf * t21; c1 = 1.0f - talf; c2 = t12 * t21;
                c3 = 1.0f - t12; c4 = r21;
            }

            float tau;
            if (USE_TAB) {
                float kc = fminf(k, 15.9f);
                unsigned bits = __float_as_uint(kc);
                int idx = (int)(bits >> 17) - 7232;
                float frac = (float)(bits & 0x1FFFFu) * (1.0f / 131072.0f);
                unsigned u = TT[idx];
                float2 Tf = __half22float2(*reinterpret_cast<const __half2*>(&u));
                tau = fmaf(frac, Tf.y, Tf.x);
            } else {
                tau = tau_exact(k);
            }

            float refl, tran;
            stokes_point(tau, c0, c1, c2, c3, c4, Nm1, refl, tran);
            out_r[rowbase + w] = refl;
            out_t[rowbase + w] = tran;
        }
    }
}

extern "C" void kernel_launch(void* const* d_in, const int* in_sizes, int n_in,
                              void* d_out, int out_size, void* d_ws, size_t ws_size,
                              hipStream_t stream) {
    const float* pN     = (const float*)d_in[0];
    const float* pcab   = (const float*)d_in[1];
    const float* pcar   = (const float*)d_in[2];
    const float* pwater = (const float*)d_in[3];
    const float* plma   = (const float*)d_in[4];
    const float* pcant  = (const float*)d_in[5];
    const float* pnr    = (const float*)d_in[6];
    const float* pkab   = (const float*)d_in[7];
    const float* pkcar  = (const float*)d_in[8];
    const float* pkant  = (const float*)d_in[9];
    const float* pkw    = (const float*)d_in[10];
    const float* pkm    = (const float*)d_in[11];
    float* out_r = (float*)d_out;
    float* out_t = out_r + (size_t)L_LEAVES * W_LAMBDA;

    dim3 grid(L_LEAVES);               // one block per leaf
    dim3 block(576);                   // 9 waves: 8 quad-waves + 1 scalar tail wave

    const size_t tab_bytes = (5 * WPAD + TAB_N) * sizeof(float);
    if (ws_size >= tab_bytes) {
        float* tabp = (float*)d_ws;
        precompute_kernel<<<(WPAD + 63) / 64, 64, 0, stream>>>(pnr, tabp);
        prospect_kernel<true><<<grid, block, 0, stream>>>(
            pN, pcab, pcar, pwater, plma, pcant, pnr,
            pkab, pkcar, pkant, pkw, pkm, (const float*)tabp, out_r, out_t);
    } else {
        prospect_kernel<false><<<grid, block, 0, stream>>>(
            pN, pcab, pcar, pwater, plma, pcant, pnr,
            pkab, pkcar, pkant, pkw, pkm, nullptr, out_r, out_t);
    }
}